// Round 3
// baseline (190.034 us; speedup 1.0000x reference)
//
#include <hip/hip_runtime.h>
#include <math.h>

#define BS 4
#define C 4
#define N 2048
#define D 16
#define KNN 32
#define M 64

typedef unsigned long long u64;
typedef unsigned int u32;
typedef unsigned short u16;
typedef float f32x2 __attribute__((ext_vector_type(2)));

// ---------------------------------------------------------------------------
// Kernel 1: exact 32-NN (sorted ascending, ties -> lower index) per (b,c,n).
// FOUR rows per wave; 32 rows (same b,c) per 512-thread block.
// R2 change: packed-FP32 distance math. v_pk_mul_f32/v_pk_add_f32 are two
// independent IEEE RTNE f32 ops per instruction (VOP3P, CDNA) -> packing two
// POINTS per lane is bit-exact vs the scalar sequence. sp is stored SoA
// (spx/spy/spz/spw) so ds_read_b64 yields (comp_j, comp_j+1) adjacent in a
// VGPR pair with no shuffles. Same 32 KB LDS; 2-lane/bank aliasing is free.
//
// Pass 1: per-lane packed min of s = -2*inner + quad_j (quad_own hoisted:
// order stats commute with the monotone map x -> round(x + quad_own), so
// pd = s_(33) + quad_own is bit-identical to the pivot on full dists).
// Pass 2: recompute full dists (bit-identical), v_cmp vs pd, ballot-prefix
// compact of survivors (typ ~46) into LDS u64 slots; rank-by-count emit of
// ranks 1..32 (rank 0 = self dropped, matching reference top-(k+1)).
// Register-light exact rescan fallback when cnt>124 (~never).
//
// Distance semantics (numpy f32, bit-exact):
//   numpy: inner = (x*x' + y*y') + z*z';  dist = ((-2*inner) + q') + q
//   here:  m2 = (-2x,-2y,-2z) (exact pow2 scale); t = (m2x*px + m2y*py)+m2z*pz
//          s = t + q'  (pass-1 key);  dist = s + q  (same association/bits)
// launch_bounds(512,6): VGPR cap ~85. LDS 40 KB/block -> 4 blocks/CU.
// ---------------------------------------------------------------------------

__device__ __forceinline__ f32x2 pk_mul(f32x2 a, f32x2 b) {
    f32x2 d;
    asm("v_pk_mul_f32 %0, %1, %2" : "=v"(d) : "v"(a), "v"(b));
    return d;
}
__device__ __forceinline__ f32x2 pk_add(f32x2 a, f32x2 b) {
    f32x2 d;
    asm("v_pk_add_f32 %0, %1, %2" : "=v"(d) : "v"(a), "v"(b));
    return d;
}

__device__ __forceinline__ u32 umin_u32(u32 a, u32 b) { return a < b ? a : b; }

#define DPP_MIN_STAGE(v, ctrl)                                                  \
    v = umin_u32(v, (u32)__builtin_amdgcn_update_dpp(                           \
                        (int)0xFFFFFFFF, (int)(v), (ctrl), 0xF, 0xF, false))

__device__ __forceinline__ u32 wave_min_dpp(u32 v) {
    DPP_MIN_STAGE(v, 0x111);
    DPP_MIN_STAGE(v, 0x112);
    DPP_MIN_STAGE(v, 0x114);
    DPP_MIN_STAGE(v, 0x118);
    DPP_MIN_STAGE(v, 0x142);
    DPP_MIN_STAGE(v, 0x143);
    return (u32)__builtin_amdgcn_readlane((int)v, 63);
}

#define DPP_ADD_STAGE(v, ctrl)                                                  \
    v += __int_as_float(__builtin_amdgcn_update_dpp(                            \
        0, __float_as_int(v), (ctrl), 0xF, 0xF, false))

__device__ __forceinline__ float wave_sum_dpp(float v) {
    DPP_ADD_STAGE(v, 0x111);
    DPP_ADD_STAGE(v, 0x112);
    DPP_ADD_STAGE(v, 0x114);
    DPP_ADD_STAGE(v, 0x118);
    DPP_ADD_STAGE(v, 0x142);
    DPP_ADD_STAGE(v, 0x143);
    return __int_as_float(__builtin_amdgcn_readlane(__float_as_int(v), 63));
}

__device__ __forceinline__ u32 mbcnt64(u64 m) {
    return __builtin_amdgcn_mbcnt_hi((u32)(m >> 32),
                                     __builtin_amdgcn_mbcnt_lo((u32)m, 0));
}

__device__ __forceinline__ float np_quad(float x, float y, float z) {
#pragma clang fp contract(off)
    float q = (x * x + y * y) + z * z;
    return q;
}

// packed query: x/y/z hold -2*comp duplicated, w holds quad_own duplicated
struct Q2 { f32x2 x, y, z, w; };

__device__ __forceinline__ Q2 make_q2(float x, float y, float z, float q) {
    Q2 r;
    float mx = -2.0f * x, my = -2.0f * y, mz = -2.0f * z;   // exact pow2 scale
    r.x.x = mx; r.x.y = mx;
    r.y.x = my; r.y.y = my;
    r.z.x = mz; r.z.y = mz;
    r.w.x = q;  r.w.y = q;
    return r;
}

// packed s-key for two points: s = ((m2x*px + m2y*py) + m2z*pz) + pw
__device__ __forceinline__ f32x2 np_s2(const Q2& q, f32x2 px, f32x2 py,
                                       f32x2 pz, f32x2 pw) {
    return pk_add(pk_add(pk_add(pk_mul(q.x, px), pk_mul(q.y, py)),
                         pk_mul(q.z, pz)),
                  pw);
}

// scalar full dist (fallback path only), same association/bits as numpy
__device__ __forceinline__ float np_dist_s(float m2x, float m2y, float m2z,
                                           float qw, float px, float py,
                                           float pz, float pw) {
#pragma clang fp contract(off)
    float t = (m2x * px + m2y * py) + m2z * pz;
    float dist = (t + pw) + qw;
    return dist;
}

__device__ __forceinline__ u32 flip_bits(float dist) {
    u32 b = __float_as_uint(dist);
    return b ^ (0x80000000u | (u32)((int)b >> 31));
}

// rank-sort survivors in sl[0..cnt) (cnt<=124) and emit ranks 1..32
__device__ __forceinline__ void emit_rank(u64* sl, int cnt, int row, int lane,
                                          u16* __restrict__ edge_ws,
                                          float* __restrict__ dist_ws) {
    if (lane < 4) sl[cnt + lane] = ~0ull;   // pads for the unroll-4 overshoot
    u64 own1 = sl[lane];
    if (lane >= cnt) own1 = ~0ull;
    int r1 = 0;
    for (int i = 0; i < cnt; i += 4) {
        u64 s0 = sl[i], s1 = sl[i + 1], s2 = sl[i + 2], s3 = sl[i + 3];
        r1 += (s0 < own1) + (s1 < own1) + (s2 < own1) + (s3 < own1);
    }
    if (r1 >= 1 && r1 <= KNN) {
        u32 fk = (u32)(own1 >> 32);
        u32 bb = (fk & 0x80000000u) ? (fk ^ 0x80000000u) : ~fk;
        edge_ws[(size_t)row * KNN + r1 - 1] = (u16)(u32)own1;
        dist_ws[(size_t)row * KNN + r1 - 1] = __uint_as_float(bb);
    }
    if (cnt > 64) {   // uncommon (~1%), wave-uniform
        u64 own2 = (64 + lane < cnt) ? sl[64 + lane] : ~0ull;
        int r2 = 0;
        for (int i = 0; i < cnt; i += 4) {
            u64 s0 = sl[i], s1 = sl[i + 1], s2 = sl[i + 2], s3 = sl[i + 3];
            r2 += (s0 < own2) + (s1 < own2) + (s2 < own2) + (s3 < own2);
        }
        if (r2 >= 1 && r2 <= KNN) {
            u32 fk = (u32)(own2 >> 32);
            u32 bb = (fk & 0x80000000u) ? (fk ^ 0x80000000u) : ~fk;
            edge_ws[(size_t)row * KNN + r2 - 1] = (u16)(u32)own2;
            dist_ws[(size_t)row * KNN + r2 - 1] = __uint_as_float(bb);
        }
    }
}

// register-light exact fallback (cnt>124, ~never): 33 rescan-extract rounds
__device__ __attribute__((noinline)) void slow_row(
    const float* spx, const float* spy, const float* spz, const float* spw,
    float m2x, float m2y, float m2z, float qw, int row, int lane,
    u16* __restrict__ edge_ws, float* __restrict__ dist_ws) {
    u64 thr = 0ull;   // all real keys are > 0 (flip==0 would require NaN dist)
    for (int s = 0; s <= KNN; ++s) {
        u64 best = ~0ull;
        for (int jj = 0; jj < 32; ++jj) {
            int j = jj * 64 + lane;
            float d = np_dist_s(m2x, m2y, m2z, qw, spx[j], spy[j], spz[j], spw[j]);
            u64 x = ((u64)flip_bits(d) << 32) | (u32)j;
            if (x > thr && x < best) best = x;
        }
        u32 bh = (u32)(best >> 32);
        u32 rh = wave_min_dpp(bh);
        u32 bl = (bh == rh) ? (u32)best : 0xFFFFFFFFu;
        u32 rl = wave_min_dpp(bl);
        thr = ((u64)rh << 32) | rl;
        if (s >= 1 && lane == s - 1) {
            u32 bb = (rh & 0x80000000u) ? (rh ^ 0x80000000u) : ~rh;
            edge_ws[(size_t)row * KNN + s - 1] = (u16)rl;
            dist_ws[(size_t)row * KNN + s - 1] = __uint_as_float(bb);
        }
    }
}

// one row's pass-2: packed dist recompute, compact survivors into sl, emit.
__device__ __forceinline__ void compact_emit(
    const float* spx, const float* spy, const float* spz, const float* spw,
    int n, float pd, u64* sl, int row, int lane,
    u16* __restrict__ edge_ws, float* __restrict__ dist_ws) {
    Q2 q = make_q2(spx[n], spy[n], spz[n], spw[n]);
    u32 base = 0;
    const int lb = lane * 2;
#pragma unroll 4
    for (int t = 0; t < 16; ++t) {
        int e0 = t * 128 + lb;
        f32x2 px = *(const f32x2*)&spx[e0];
        f32x2 py = *(const f32x2*)&spy[e0];
        f32x2 pz = *(const f32x2*)&spz[e0];
        f32x2 pw = *(const f32x2*)&spw[e0];
        f32x2 d  = pk_add(np_s2(q, px, py, pz, pw), q.w);   // full dist pair
        {   // element 0: point j = e0
            bool s = d.x <= pd;
            u64 m = __ballot(s);
            u32 pos = base + mbcnt64(m);
            if (s && pos < 128) sl[pos] = ((u64)flip_bits(d.x) << 32) | (u32)e0;
            base += (u32)__popcll(m);
        }
        {   // element 1: point j = e0 + 1
            bool s = d.y <= pd;
            u64 m = __ballot(s);
            u32 pos = base + mbcnt64(m);
            if (s && pos < 128) sl[pos] = ((u64)flip_bits(d.y) << 32) | (u32)(e0 + 1);
            base += (u32)__popcll(m);
        }
    }
    if ((int)base <= 124) emit_rank(sl, (int)base, row, lane, edge_ws, dist_ws);
    else slow_row(spx, spy, spz, spw, q.x.x, q.y.x, q.z.x, q.w.x, row, lane,
                  edge_ws, dist_ws);
}

__global__ __launch_bounds__(512, 6) void knn_kernel(const float* __restrict__ pos,
                                                     u16* __restrict__ edge_ws,
                                                     float* __restrict__ dist_ws,
                                                     const float* __restrict__ aw,
                                                     const float* __restrict__ sw,
                                                     float* __restrict__ aw4,
                                                     float* __restrict__ sw4) {
    __shared__ __align__(16) float spx[N];   // SoA: 4 x 8 KB = 32 KB
    __shared__ __align__(16) float spy[N];
    __shared__ __align__(16) float spz[N];
    __shared__ __align__(16) float spw[N];
    __shared__ u64 slots[8][128];            // 8 KB (shared by a wave's rows)
    const int tid  = threadIdx.x;
    const int lane = tid & 63;
    const int wave = tid >> 6;          // 0..7
    const int rb   = blockIdx.x * 32;   // 32 rows per block, same (b,c)
    const int bc   = rb >> 11;

    const float* posr = pos + (size_t)bc * (N * 3);
    for (int j = tid; j < N; j += 512) {
        float x = posr[3 * j], y = posr[3 * j + 1], z = posr[3 * j + 2];
        spx[j] = x; spy[j] = y; spz[j] = z; spw[j] = np_quad(x, y, z);
    }

    // fused prep (block 0 only): repack weights into [f/4][m][f%4]
    if (blockIdx.x == 0) {
#pragma unroll
        for (int it = 0; it < 16; ++it) {
            int i = it * 512 + tid;           // i = f*64 + m
            int f = i >> 6, mm = i & 63;
            int idx = (f >> 2) * 256 + mm * 4 + (f & 3);
            aw4[idx] = aw[mm * 128 + f];
            sw4[idx] = sw[i];
        }
    }
    __syncthreads();

    const int rowA = rb + wave * 4;
    const int nA   = rowA & (N - 1);        // nA..nA+3 same (b,c), no wrap
    const Q2 qA = make_q2(spx[nA],     spy[nA],     spz[nA],     spw[nA]);
    const Q2 qB = make_q2(spx[nA + 1], spy[nA + 1], spz[nA + 1], spw[nA + 1]);
    const Q2 qC = make_q2(spx[nA + 2], spy[nA + 2], spz[nA + 2], spw[nA + 2]);
    const Q2 qD = make_q2(spx[nA + 3], spy[nA + 3], spz[nA + 3], spw[nA + 3]);

    // ---- pass 1: packed per-lane min of s-keys, 2 points/lane/step ----
    f32x2 mnA, mnB, mnC, mnD;
    mnA.x = mnA.y = __builtin_inff();
    mnB.x = mnB.y = __builtin_inff();
    mnC.x = mnC.y = __builtin_inff();
    mnD.x = mnD.y = __builtin_inff();
    const int lb = lane * 2;
#pragma unroll
    for (int t = 0; t < 16; ++t) {
        int e0 = t * 128 + lb;
        f32x2 px = *(const f32x2*)&spx[e0];
        f32x2 py = *(const f32x2*)&spy[e0];
        f32x2 pz = *(const f32x2*)&spz[e0];
        f32x2 pw = *(const f32x2*)&spw[e0];
        f32x2 sA = np_s2(qA, px, py, pz, pw);
        f32x2 sB = np_s2(qB, px, py, pz, pw);
        f32x2 sC = np_s2(qC, px, py, pz, pw);
        f32x2 sD = np_s2(qD, px, py, pz, pw);
        mnA.x = fminf(mnA.x, sA.x); mnA.y = fminf(mnA.y, sA.y);
        mnB.x = fminf(mnB.x, sB.x); mnB.y = fminf(mnB.y, sB.y);
        mnC.x = fminf(mnC.x, sC.x); mnC.y = fminf(mnC.y, sC.y);
        mnD.x = fminf(mnD.x, sD.x); mnD.y = fminf(mnD.y, sD.y);
    }

    // ---- pivots: 33rd-smallest lane min (interleaved float bitonic) ----
    float vA = fminf(mnA.x, mnA.y), vB = fminf(mnB.x, mnB.y);
    float vC = fminf(mnC.x, mnC.y), vD = fminf(mnD.x, mnD.y);
#pragma unroll
    for (int k = 2; k <= 64; k <<= 1) {
#pragma unroll
        for (int j = k >> 1; j > 0; j >>= 1) {
            bool keepmin = (((lane & k) == 0) == ((lane & j) == 0));
            float oA = __int_as_float(__shfl_xor(__float_as_int(vA), j));
            float oB = __int_as_float(__shfl_xor(__float_as_int(vB), j));
            float oC = __int_as_float(__shfl_xor(__float_as_int(vC), j));
            float oD = __int_as_float(__shfl_xor(__float_as_int(vD), j));
            vA = ((oA < vA) == keepmin) ? oA : vA;
            vB = ((oB < vB) == keepmin) ? oB : vB;
            vC = ((oC < vC) == keepmin) ? oC : vC;
            vD = ((oD < vD) == keepmin) ? oD : vD;
        }
    }
    // pd = round(s_(33) + quad_own): bit-identical to the pivot on full dists
    // (order stats commute with the monotone map x -> round(x + c))
    float pdA, pdB, pdC, pdD;
    {
#pragma clang fp contract(off)
        pdA = __int_as_float(__builtin_amdgcn_readlane(__float_as_int(vA), 32)) + qA.w.x;
        pdB = __int_as_float(__builtin_amdgcn_readlane(__float_as_int(vB), 32)) + qB.w.x;
        pdC = __int_as_float(__builtin_amdgcn_readlane(__float_as_int(vC), 32)) + qC.w.x;
        pdD = __int_as_float(__builtin_amdgcn_readlane(__float_as_int(vD), 32)) + qD.w.x;
    }

    // ---- pass 2: sequential per row, shared slot buffer ----
    compact_emit(spx, spy, spz, spw, nA,     pdA, slots[wave], rowA,     lane, edge_ws, dist_ws);
    compact_emit(spx, spy, spz, spw, nA + 1, pdB, slots[wave], rowA + 1, lane, edge_ws, dist_ws);
    compact_emit(spx, spy, spz, spw, nA + 2, pdC, slots[wave], rowA + 2, lane, edge_ws, dist_ws);
    compact_emit(spx, spy, spz, spw, nA + 3, pdD, slots[wave], rowA + 3, lane, edge_ws, dist_ws);
}

// ---------------------------------------------------------------------------
// Kernel 2: angle features + gate + gated aggregation + two 128->64 matvecs.
// One wave per (b,n); 8 consecutive n (same b) per 512-thread block.
// All intermediates wave-private in LDS -> only ONE barrier (outv transpose).
// Phase C: float4 weights from global (VMEM pipe) x float4 theta/h broadcast
// from LDS; unroll 4 to bound in-flight float4 register pressure.
// ---------------------------------------------------------------------------
__global__ __launch_bounds__(512) void conv_kernel(
    const float* __restrict__ pos, const float* __restrict__ node_fea,
    const float* __restrict__ node_mask, const float* __restrict__ aw4,
    const float* __restrict__ sw4, const float* __restrict__ w1,
    const float* __restrict__ w2, const u16* __restrict__ edge_ws,
    const float* __restrict__ dist_ws, float* __restrict__ out) {
    __shared__ __align__(16) float theta_lds[8][128];  // [wave][f], f=kk*4+cc
    __shared__ float gate_lds[8][128];                 // [wave][cc*32+kk]
    __shared__ u16   edge_lds[8][128];                 // [wave][cc*32+kk]
    __shared__ __align__(16) float h_lds[8][128];      // [wave][f], f=cc*32+..
    __shared__ float gsum_lds[8][4];                   // [wave][cc]
    __shared__ float outv[8][65];                      // [n-offset][m], padded

    const int tid  = threadIdx.x;
    const int lane = tid & 63;
    const int wave = tid >> 6;             // 0..7

    const int row0 = blockIdx.x * 8;   // (b,n) row base, same b across block
    const int b    = row0 >> 11;
    const int n0   = row0 & (N - 1);
    const int row  = row0 + wave;
    const int n    = row & (N - 1);
    const float mval = node_mask[b * N + n];

    // gate scalar S = sum_m relu(w1[m]) * w2[m]
    float S = wave_sum_dpp(fmaxf(w1[lane], 0.f) * w2[lane]);

    // ---- Phase A: per (cc,kk) pair: direction, theta, gate (wave-private) ----
#pragma unroll
    for (int it = 0; it < 2; ++it) {
        int p  = it * 64 + lane;
        int cc = p >> 5, kk = p & 31;
        int rowc = (b * C + cc) * N + n;
        int e      = edge_ws[(size_t)rowc * KNN + kk];
        float dist = dist_ws[(size_t)rowc * KNN + kk];
        const float* pp = pos + (size_t)rowc * 3;
        const float* qp = pos + ((size_t)(b * C + cc) * N + e) * 3;
        float dx = qp[0] - pp[0], dy = qp[1] - pp[1], dz = qp[2] - pp[2];
        float nrm = fmaxf(sqrtf(dx * dx + dy * dy + dz * dz), 1e-12f);
        float inv = 1.0f / nrm;
        dx *= inv; dy *= inv; dz *= inv;
        int src = lane & 32;   // lane holding kk==0 for this cc-group
        float n0x = __shfl(dx, src), n0y = __shfl(dy, src), n0z = __shfl(dz, src);
        float cosv = (kk == 0) ? 1.f : (dx * n0x + dy * n0y + dz * n0z);
        theta_lds[wave][kk * 4 + cc] = cosv * mval;

        float g = fmaxf(dist * S, 0.f) * mval;
        float gate = 1.f / (1.f + expf(-g));
        gate_lds[wave][cc * 32 + kk] = gate;
        edge_lds[wave][cc * 32 + kk] = (u16)e;
        float gs = gate;
#pragma unroll
        for (int off = 1; off < 32; off <<= 1) gs += __shfl_xor(gs, off);
        if (kk == 0) gsum_lds[wave][cc] = gs;
    }

    // ---- Phase B: h[f] = sum_k gate * fea_cat (all 64 lanes gather) ----
    {
        int cc = lane >> 4, dd = lane & 15;
        const float* nf = node_fea + (size_t)(b * C + cc) * N * D;
        float own = nf[(size_t)n * D + dd];
        h_lds[wave][cc * 32 + dd] = own * mval * gsum_lds[wave][cc];
        float acc = 0.f;
#pragma unroll
        for (int k = 0; k < 32; ++k) {
            int e = edge_lds[wave][cc * 32 + k];
            acc += gate_lds[wave][cc * 32 + k] * nf[(size_t)e * D + dd];
        }
        h_lds[wave][cc * 32 + 16 + dd] = acc * mval;
    }

    // ---- Phase C: m = lane; two 128->64 matvecs (float4) + epilogue ----
    {
        const float4* wa4 = (const float4*)aw4;
        const float4* wv4 = (const float4*)sw4;
        const float4* th4 = (const float4*)(&theta_lds[wave][0]);
        const float4* hh4 = (const float4*)(&h_lds[wave][0]);
        float fs = 0.f, fe = 0.f;
#pragma unroll 4
        for (int f4 = 0; f4 < 32; ++f4) {
            float4 wa = wa4[f4 * 64 + lane];
            float4 wv = wv4[f4 * 64 + lane];
            float4 tv = th4[f4];
            float4 hv = hh4[f4];
            fs += wa.x * tv.x + wa.y * tv.y + wa.z * tv.z + wa.w * tv.w;
            fe += wv.x * hv.x + wv.y * hv.y + wv.z * hv.z + wv.w * hv.w;
        }
        float v = fs + fe;
        v = (v > 0.f) ? v : 0.01f * v;
        outv[wave][lane] = v * mval;
    }
    __syncthreads();   // the only cross-wave handoff (outv transpose)

    // store: thread t -> m = t>>3, n-offset j = t&7
    {
        int m = tid >> 3, j = tid & 7;
        out[((size_t)(b * 64 + m)) * N + n0 + j] = outv[j][m];
    }
}

// ---------------------------------------------------------------------------
extern "C" void kernel_launch(void* const* d_in, const int* in_sizes, int n_in,
                              void* d_out, int out_size, void* d_ws, size_t ws_size,
                              hipStream_t stream) {
    const float* pos       = (const float*)d_in[0];
    const float* node_fea  = (const float*)d_in[1];
    const float* node_mask = (const float*)d_in[2];
    const float* aw        = (const float*)d_in[3];
    const float* sw        = (const float*)d_in[4];
    const float* w1        = (const float*)d_in[5];
    const float* w2        = (const float*)d_in[6];
    float* out = (float*)d_out;

    // ws: dist f32 4 MB | edge u16 2 MB | aw4 32 KB | sw4 32 KB  (~6.1 MB)
    float* dist_ws = (float*)d_ws;
    u16*   edge_ws = (u16*)((char*)d_ws + 4u * 1024 * 1024);
    float* aw4     = (float*)((char*)d_ws + 6u * 1024 * 1024);
    float* sw4     = (float*)((char*)d_ws + 6u * 1024 * 1024 + 32u * 1024);

    knn_kernel<<<BS * C * N / 32, 512, 0, stream>>>(pos, edge_ws, dist_ws,
                                                    aw, sw, aw4, sw4);
    conv_kernel<<<BS * N / 8, 512, 0, stream>>>(pos, node_fea, node_mask, aw4, sw4,
                                                w1, w2, edge_ws, dist_ws, out);
}

// Round 7
// 145.906 us; speedup vs baseline: 1.3024x; 1.3024x over previous
//
#include <hip/hip_runtime.h>
#include <math.h>

#define BS 4
#define C 4
#define N 2048
#define D 16
#define KNN 32
#define M 64

typedef unsigned long long u64;
typedef unsigned int u32;
typedef unsigned short u16;

// ---------------------------------------------------------------------------
// Kernel 1: exact 32-NN (sorted ascending, ties -> lower index) per (b,c,n).
// TWO rows per wave; 16 rows (same b,c) per 512-thread block.  (R3 note:
// 4-row variant measured SLOWER (70 vs ~61 us knn); packed v_pk_f32 variant
// caused 10x HBM traffic (scratch spill) -> both reverted. This is the
// proven 2-row structure + two bit-exact arithmetic folds.)
//
// Pass 1: per-lane v_min_f32 of s = -2*inner + quad_j (quad_own hoisted out:
// order statistics commute with the monotone map x -> round(x + quad_own),
// so pd = (33rd-smallest lane-min of s) + quad_own is BIT-IDENTICAL to the
// pivot computed on full dists). Pivot via interleaved float bitonic.
// Guarantee: >=33 keys have dist<=pd, so the top-33 always survive.
// Pass 2: recompute dists (bit-identical, full form), v_cmp_le_f32 vs pd,
// exec-masked ballot-prefix compact of survivors (typ. ~46) into LDS as u64;
// rank-sort via broadcast ds_read + u64 compares; ranks 1..32 store (rank 0
// dropped = reference top-(k+1)). Register-light exact rescan fallback when
// cnt>124 (~never).
//
// Distance arithmetic replicates numpy f32 semantics bit-exactly, with the
// -2 folded into the query point (power-of-2 scaling is exact and commutes
// with round-to-nearest; data is far from subnormal, no overflow):
//   numpy: inner = (x*x' + y*y') + z*z';  dist = ((-2*inner) + q') + q
//   here:  m2 = (-2x,-2y,-2z);  t = (m2.x*x' + m2.y*y') + m2.z*z'  == -2*inner
//          s = t + q'  (pass-1 key);  dist = s + q  (same association, bits)
// launch_bounds(512,6): VGPR cap ~85 (R12's (512,8) forced VGPR=32 -> 200 MB
// scratch spill). Block 0 additionally repacks aw4/sw4 (fused prep).
// ---------------------------------------------------------------------------

__device__ __forceinline__ u32 umin_u32(u32 a, u32 b) { return a < b ? a : b; }

#define DPP_MIN_STAGE(v, ctrl)                                                  \
    v = umin_u32(v, (u32)__builtin_amdgcn_update_dpp(                           \
                        (int)0xFFFFFFFF, (int)(v), (ctrl), 0xF, 0xF, false))

__device__ __forceinline__ u32 wave_min_dpp(u32 v) {
    DPP_MIN_STAGE(v, 0x111);
    DPP_MIN_STAGE(v, 0x112);
    DPP_MIN_STAGE(v, 0x114);
    DPP_MIN_STAGE(v, 0x118);
    DPP_MIN_STAGE(v, 0x142);
    DPP_MIN_STAGE(v, 0x143);
    return (u32)__builtin_amdgcn_readlane((int)v, 63);
}

#define DPP_ADD_STAGE(v, ctrl)                                                  \
    v += __int_as_float(__builtin_amdgcn_update_dpp(                            \
        0, __float_as_int(v), (ctrl), 0xF, 0xF, false))

__device__ __forceinline__ float wave_sum_dpp(float v) {
    DPP_ADD_STAGE(v, 0x111);
    DPP_ADD_STAGE(v, 0x112);
    DPP_ADD_STAGE(v, 0x114);
    DPP_ADD_STAGE(v, 0x118);
    DPP_ADD_STAGE(v, 0x142);
    DPP_ADD_STAGE(v, 0x143);
    return __int_as_float(__builtin_amdgcn_readlane(__float_as_int(v), 63));
}

__device__ __forceinline__ u32 mbcnt64(u64 m) {
    return __builtin_amdgcn_mbcnt_hi((u32)(m >> 32),
                                     __builtin_amdgcn_mbcnt_lo((u32)m, 0));
}

__device__ __forceinline__ float np_quad(float x, float y, float z) {
#pragma clang fp contract(off)
    float q = (x * x + y * y) + z * z;
    return q;
}

// pass-1 key: s = -2*inner + quad_j  (bit-exact prefix of the full dist)
__device__ __forceinline__ float np_s(const float4& m2, const float4& p) {
#pragma clang fp contract(off)
    float t = (m2.x * p.x + m2.y * p.y) + m2.z * p.z;   // == -2*inner, bit-exact
    float s = t + p.w;
    return s;
}

// full dist: (s + quad_own), same association/bits as numpy
__device__ __forceinline__ float np_dist2(const float4& m2, const float4& p) {
#pragma clang fp contract(off)
    float dist = np_s(m2, p) + m2.w;
    return dist;
}

__device__ __forceinline__ float4 fold_m2(const float4& me) {
    return make_float4(-2.0f * me.x, -2.0f * me.y, -2.0f * me.z, me.w);
}

__device__ __forceinline__ u32 flip_bits(float dist) {
    u32 b = __float_as_uint(dist);
    return b ^ (0x80000000u | (u32)((int)b >> 31));
}

__device__ __forceinline__ u64 dist_key(float dist, int j) {
    return ((u64)flip_bits(dist) << 32) | (u32)j;
}

// rank-sort survivors in sl[0..cnt) (cnt<=124) and emit ranks 1..32
__device__ __forceinline__ void emit_rank(u64* sl, int cnt, int row, int lane,
                                          u16* __restrict__ edge_ws,
                                          float* __restrict__ dist_ws) {
    if (lane < 4) sl[cnt + lane] = ~0ull;   // pads for the unroll-4 overshoot
    u64 own1 = sl[lane];
    if (lane >= cnt) own1 = ~0ull;
    int r1 = 0;
    for (int i = 0; i < cnt; i += 4) {
        u64 s0 = sl[i], s1 = sl[i + 1], s2 = sl[i + 2], s3 = sl[i + 3];
        r1 += (s0 < own1) + (s1 < own1) + (s2 < own1) + (s3 < own1);
    }
    if (r1 >= 1 && r1 <= KNN) {
        u32 fk = (u32)(own1 >> 32);
        u32 bb = (fk & 0x80000000u) ? (fk ^ 0x80000000u) : ~fk;
        edge_ws[(size_t)row * KNN + r1 - 1] = (u16)(u32)own1;
        dist_ws[(size_t)row * KNN + r1 - 1] = __uint_as_float(bb);
    }
    if (cnt > 64) {   // uncommon (~1%), wave-uniform
        u64 own2 = (64 + lane < cnt) ? sl[64 + lane] : ~0ull;
        int r2 = 0;
        for (int i = 0; i < cnt; i += 4) {
            u64 s0 = sl[i], s1 = sl[i + 1], s2 = sl[i + 2], s3 = sl[i + 3];
            r2 += (s0 < own2) + (s1 < own2) + (s2 < own2) + (s3 < own2);
        }
        if (r2 >= 1 && r2 <= KNN) {
            u32 fk = (u32)(own2 >> 32);
            u32 bb = (fk & 0x80000000u) ? (fk ^ 0x80000000u) : ~fk;
            edge_ws[(size_t)row * KNN + r2 - 1] = (u16)(u32)own2;
            dist_ws[(size_t)row * KNN + r2 - 1] = __uint_as_float(bb);
        }
    }
}

// register-light exact fallback (cnt>124, ~never): 33 rescan-extract rounds
__device__ __attribute__((noinline)) void slow_row(const float4* sp, float4 m2,
                                                   int row, int lane,
                                                   u16* __restrict__ edge_ws,
                                                   float* __restrict__ dist_ws) {
    u64 thr = 0ull;   // all real keys are > 0 (flip==0 would require NaN dist)
    for (int s = 0; s <= KNN; ++s) {
        u64 best = ~0ull;
        for (int jj = 0; jj < 32; ++jj) {
            int j = jj * 64 + lane;
            u64 x = dist_key(np_dist2(m2, sp[j]), j);
            if (x > thr && x < best) best = x;
        }
        u32 bh = (u32)(best >> 32);
        u32 rh = wave_min_dpp(bh);
        u32 bl = (bh == rh) ? (u32)best : 0xFFFFFFFFu;
        u32 rl = wave_min_dpp(bl);
        thr = ((u64)rh << 32) | rl;
        if (s >= 1 && lane == s - 1) {
            u32 bb = (rh & 0x80000000u) ? (rh ^ 0x80000000u) : ~rh;
            edge_ws[(size_t)row * KNN + s - 1] = (u16)rl;
            dist_ws[(size_t)row * KNN + s - 1] = __uint_as_float(bb);
        }
    }
}

// one row's pass-2: compact survivors (dist<=pd, float compare) into sl, emit
__device__ __forceinline__ void compact_emit(const float4* sp, float4 m2, float pd,
                                             u64* sl, int row, int lane,
                                             u16* __restrict__ edge_ws,
                                             float* __restrict__ dist_ws) {
    u32 base = 0;
#pragma unroll 2
    for (int jj = 0; jj < 32; ++jj) {
        int j = jj * 64 + lane;
        float d = np_dist2(m2, sp[j]);
        bool s = d <= pd;
        u64 m = __ballot(s);
        u32 pos = base + mbcnt64(m);
        if (s && pos < 128) sl[pos] = ((u64)flip_bits(d) << 32) | (u32)j;
        base += (u32)__popcll(m);
    }
    if ((int)base <= 124) emit_rank(sl, (int)base, row, lane, edge_ws, dist_ws);
    else                  slow_row(sp, m2, row, lane, edge_ws, dist_ws);
}

__global__ __launch_bounds__(512, 6) void knn_kernel(const float* __restrict__ pos,
                                                     u16* __restrict__ edge_ws,
                                                     float* __restrict__ dist_ws,
                                                     const float* __restrict__ aw,
                                                     const float* __restrict__ sw,
                                                     float* __restrict__ aw4,
                                                     float* __restrict__ sw4) {
    __shared__ float4 sp[N];          // 32 KB
    __shared__ u64 slots[8][128];     // 8 KB (shared by a wave's two rows)
    const int tid  = threadIdx.x;
    const int lane = tid & 63;
    const int wave = tid >> 6;          // 0..7
    const int rb   = blockIdx.x * 16;   // 16 rows per block, same (b,c)
    const int bc   = rb >> 11;

    const float* posr = pos + (size_t)bc * (N * 3);
    for (int j = tid; j < N; j += 512) {
        float x = posr[3 * j], y = posr[3 * j + 1], z = posr[3 * j + 2];
        sp[j] = make_float4(x, y, z, np_quad(x, y, z));
    }

    // fused prep (block 0 only): repack weights into [f/4][m][f%4]
    if (blockIdx.x == 0) {
#pragma unroll
        for (int it = 0; it < 16; ++it) {
            int i = it * 512 + tid;           // i = f*64 + m
            int f = i >> 6, mm = i & 63;
            int idx = (f >> 2) * 256 + mm * 4 + (f & 3);
            aw4[idx] = aw[mm * 128 + f];
            sw4[idx] = sw[i];
        }
    }
    __syncthreads();

    const int rowA = rb + wave * 2, rowB = rowA + 1;
    const int nA = rowA & (N - 1), nB = nA + 1;
    const float4 m2A = fold_m2(sp[nA]);
    const float4 m2B = fold_m2(sp[nB]);

    // ---- pass 1: per-lane float min of s-keys, both rows ----
    float mnA = __builtin_inff(), mnB = __builtin_inff();
#pragma unroll 8
    for (int jj = 0; jj < 32; ++jj) {
        int j = jj * 64 + lane;
        float4 p = sp[j];
        mnA = fminf(mnA, np_s(m2A, p));
        mnB = fminf(mnB, np_s(m2B, p));
    }

    // ---- pivots: 33rd-smallest lane min (interleaved float bitonic) ----
    float vA = mnA, vB = mnB;
#pragma unroll
    for (int k = 2; k <= 64; k <<= 1) {
#pragma unroll
        for (int j = k >> 1; j > 0; j >>= 1) {
            float oA = __int_as_float(__shfl_xor(__float_as_int(vA), j));
            float oB = __int_as_float(__shfl_xor(__float_as_int(vB), j));
            bool keepmin = (((lane & k) == 0) == ((lane & j) == 0));
            vA = ((oA < vA) == keepmin) ? oA : vA;
            vB = ((oB < vB) == keepmin) ? oB : vB;
        }
    }
    // pd = round(s_(33) + quad_own): bit-identical to the pivot on full dists
    // (order stats commute with the monotone map x -> round(x + c))
    float pdA, pdB;
    {
#pragma clang fp contract(off)
        pdA = __int_as_float(__builtin_amdgcn_readlane(__float_as_int(vA), 32)) + m2A.w;
        pdB = __int_as_float(__builtin_amdgcn_readlane(__float_as_int(vB), 32)) + m2B.w;
    }

    // ---- pass 2: sequential per row, shared slot buffer ----
    compact_emit(sp, m2A, pdA, slots[wave], rowA, lane, edge_ws, dist_ws);
    compact_emit(sp, m2B, pdB, slots[wave], rowB, lane, edge_ws, dist_ws);
}

// ---------------------------------------------------------------------------
// Kernel 2: angle features + gate + gated aggregation + two 128->64 matvecs.
// One wave per (b,n); 8 consecutive n (same b) per 512-thread block.
// All intermediates wave-private in LDS -> only ONE barrier (outv transpose).
// Phase C: float4 weights from global (VMEM pipe) x float4 theta/h broadcast
// from LDS; unroll 4 to bound in-flight float4 register pressure.
// ---------------------------------------------------------------------------
__global__ __launch_bounds__(512) void conv_kernel(
    const float* __restrict__ pos, const float* __restrict__ node_fea,
    const float* __restrict__ node_mask, const float* __restrict__ aw4,
    const float* __restrict__ sw4, const float* __restrict__ w1,
    const float* __restrict__ w2, const u16* __restrict__ edge_ws,
    const float* __restrict__ dist_ws, float* __restrict__ out) {
    __shared__ __align__(16) float theta_lds[8][128];  // [wave][f], f=kk*4+cc
    __shared__ float gate_lds[8][128];                 // [wave][cc*32+kk]
    __shared__ u16   edge_lds[8][128];                 // [wave][cc*32+kk]
    __shared__ __align__(16) float h_lds[8][128];      // [wave][f], f=cc*32+..
    __shared__ float gsum_lds[8][4];                   // [wave][cc]
    __shared__ float outv[8][65];                      // [n-offset][m], padded

    const int tid  = threadIdx.x;
    const int lane = tid & 63;
    const int wave = tid >> 6;             // 0..7

    const int row0 = blockIdx.x * 8;   // (b,n) row base, same b across block
    const int b    = row0 >> 11;
    const int n0   = row0 & (N - 1);
    const int row  = row0 + wave;
    const int n    = row & (N - 1);
    const float mval = node_mask[b * N + n];

    // gate scalar S = sum_m relu(w1[m]) * w2[m]
    float S = wave_sum_dpp(fmaxf(w1[lane], 0.f) * w2[lane]);

    // ---- Phase A: per (cc,kk) pair: direction, theta, gate (wave-private) ----
#pragma unroll
    for (int it = 0; it < 2; ++it) {
        int p  = it * 64 + lane;
        int cc = p >> 5, kk = p & 31;
        int rowc = (b * C + cc) * N + n;
        int e      = edge_ws[(size_t)rowc * KNN + kk];
        float dist = dist_ws[(size_t)rowc * KNN + kk];
        const float* pp = pos + (size_t)rowc * 3;
        const float* qp = pos + ((size_t)(b * C + cc) * N + e) * 3;
        float dx = qp[0] - pp[0], dy = qp[1] - pp[1], dz = qp[2] - pp[2];
        float nrm = fmaxf(sqrtf(dx * dx + dy * dy + dz * dz), 1e-12f);
        float inv = 1.0f / nrm;
        dx *= inv; dy *= inv; dz *= inv;
        int src = lane & 32;   // lane holding kk==0 for this cc-group
        float n0x = __shfl(dx, src), n0y = __shfl(dy, src), n0z = __shfl(dz, src);
        float cosv = (kk == 0) ? 1.f : (dx * n0x + dy * n0y + dz * n0z);
        theta_lds[wave][kk * 4 + cc] = cosv * mval;

        float g = fmaxf(dist * S, 0.f) * mval;
        float gate = 1.f / (1.f + expf(-g));
        gate_lds[wave][cc * 32 + kk] = gate;
        edge_lds[wave][cc * 32 + kk] = (u16)e;
        float gs = gate;
#pragma unroll
        for (int off = 1; off < 32; off <<= 1) gs += __shfl_xor(gs, off);
        if (kk == 0) gsum_lds[wave][cc] = gs;
    }

    // ---- Phase B: h[f] = sum_k gate * fea_cat (all 64 lanes gather) ----
    {
        int cc = lane >> 4, dd = lane & 15;
        const float* nf = node_fea + (size_t)(b * C + cc) * N * D;
        float own = nf[(size_t)n * D + dd];
        h_lds[wave][cc * 32 + dd] = own * mval * gsum_lds[wave][cc];
        float acc = 0.f;
#pragma unroll
        for (int k = 0; k < 32; ++k) {
            int e = edge_lds[wave][cc * 32 + k];
            acc += gate_lds[wave][cc * 32 + k] * nf[(size_t)e * D + dd];
        }
        h_lds[wave][cc * 32 + 16 + dd] = acc * mval;
    }

    // ---- Phase C: m = lane; two 128->64 matvecs (float4) + epilogue ----
    {
        const float4* wa4 = (const float4*)aw4;
        const float4* wv4 = (const float4*)sw4;
        const float4* th4 = (const float4*)(&theta_lds[wave][0]);
        const float4* hh4 = (const float4*)(&h_lds[wave][0]);
        float fs = 0.f, fe = 0.f;
#pragma unroll 4
        for (int f4 = 0; f4 < 32; ++f4) {
            float4 wa = wa4[f4 * 64 + lane];
            float4 wv = wv4[f4 * 64 + lane];
            float4 tv = th4[f4];
            float4 hv = hh4[f4];
            fs += wa.x * tv.x + wa.y * tv.y + wa.z * tv.z + wa.w * tv.w;
            fe += wv.x * hv.x + wv.y * hv.y + wv.z * hv.z + wv.w * hv.w;
        }
        float v = fs + fe;
        v = (v > 0.f) ? v : 0.01f * v;
        outv[wave][lane] = v * mval;
    }
    __syncthreads();   // the only cross-wave handoff (outv transpose)

    // store: thread t -> m = t>>3, n-offset j = t&7
    {
        int m = tid >> 3, j = tid & 7;
        out[((size_t)(b * 64 + m)) * N + n0 + j] = outv[j][m];
    }
}

// ---------------------------------------------------------------------------
extern "C" void kernel_launch(void* const* d_in, const int* in_sizes, int n_in,
                              void* d_out, int out_size, void* d_ws, size_t ws_size,
                              hipStream_t stream) {
    const float* pos       = (const float*)d_in[0];
    const float* node_fea  = (const float*)d_in[1];
    const float* node_mask = (const float*)d_in[2];
    const float* aw        = (const float*)d_in[3];
    const float* sw        = (const float*)d_in[4];
    const float* w1        = (const float*)d_in[5];
    const float* w2        = (const float*)d_in[6];
    float* out = (float*)d_out;

    // ws: dist f32 4 MB | edge u16 2 MB | aw4 32 KB | sw4 32 KB  (~6.1 MB)
    float* dist_ws = (float*)d_ws;
    u16*   edge_ws = (u16*)((char*)d_ws + 4u * 1024 * 1024);
    float* aw4     = (float*)((char*)d_ws + 6u * 1024 * 1024);
    float* sw4     = (float*)((char*)d_ws + 6u * 1024 * 1024 + 32u * 1024);

    knn_kernel<<<BS * C * N / 16, 512, 0, stream>>>(pos, edge_ws, dist_ws,
                                                    aw, sw, aw4, sw4);
    conv_kernel<<<BS * N / 8, 512, 0, stream>>>(pos, node_fea, node_mask, aw4, sw4,
                                                w1, w2, edge_ws, dist_ws, out);
}

// Round 11
// 141.978 us; speedup vs baseline: 1.3385x; 1.0277x over previous
//
#include <hip/hip_runtime.h>
#include <math.h>

#define BS 4
#define C 4
#define N 2048
#define D 16
#define KNN 32
#define M 64

typedef unsigned long long u64;
typedef unsigned int u32;
typedef unsigned short u16;

// ---------------------------------------------------------------------------
// Kernel 1: exact 32-NN (sorted ascending, ties -> lower index) per (b,c,n).
// TWO rows per wave; 16 rows (same b,c) per 512-thread block.
// R7 measured: 62.6 us knn, VALUBusy 83-87%, HBM 1.5% -> pure VALU-bound.
// R8/R9 change: cache the 32 per-lane s-keys per row in REGISTERS during
// pass 1 (fully unrolled, static indices -> no scratch). Pass 2 then needs
// only d = s_cache[jj] + q (1 add, same association/bits as before) instead
// of the 6-op recompute + ds_read_b128. Saves ~320 VALU + 64 DS reads/wave.
// VGPR ~40 -> ~104: launch_bounds(512,4) (VGPR cap 128). LDS still 40 KB.
// (R9: fixed '#pragma clang fp' placement -> np_add helper.)
//
// Pass 1: per-lane v_min_f32 of s = -2*inner + quad_j (quad_own hoisted out:
// order statistics commute with the monotone map x -> round(x + quad_own),
// so pd = (33rd-smallest lane-min of s) + quad_own is BIT-IDENTICAL to the
// pivot computed on full dists). Pivot via interleaved float bitonic.
// Guarantee: >=33 keys have dist<=pd, so the top-33 always survive.
// Pass 2: d = s_cache + q (bit-identical), v_cmp_le_f32 vs pd, exec-masked
// ballot-prefix compact of survivors (typ. ~46) into LDS as u64; rank-sort
// via broadcast ds_read + u64 compares; ranks 1..32 store (rank 0 dropped =
// reference top-(k+1)). Register-light exact rescan fallback when cnt>124.
//
// Distance arithmetic replicates numpy f32 semantics bit-exactly, with the
// -2 folded into the query point (power-of-2 scaling is exact and commutes
// with round-to-nearest; data is far from subnormal, no overflow):
//   numpy: inner = (x*x' + y*y') + z*z';  dist = ((-2*inner) + q') + q
//   here:  m2 = (-2x,-2y,-2z);  t = (m2.x*x' + m2.y*y') + m2.z*z'  == -2*inner
//          s = t + q'  (pass-1 key);  dist = s + q  (same association, bits)
// History: 4-row/wave = slower (70 us); packed v_pk_f32 = spill, 10x HBM
// (102 us); both reverted. Block 0 additionally repacks aw4/sw4 (fused prep).
// ---------------------------------------------------------------------------

__device__ __forceinline__ u32 umin_u32(u32 a, u32 b) { return a < b ? a : b; }

#define DPP_MIN_STAGE(v, ctrl)                                                  \
    v = umin_u32(v, (u32)__builtin_amdgcn_update_dpp(                           \
                        (int)0xFFFFFFFF, (int)(v), (ctrl), 0xF, 0xF, false))

__device__ __forceinline__ u32 wave_min_dpp(u32 v) {
    DPP_MIN_STAGE(v, 0x111);
    DPP_MIN_STAGE(v, 0x112);
    DPP_MIN_STAGE(v, 0x114);
    DPP_MIN_STAGE(v, 0x118);
    DPP_MIN_STAGE(v, 0x142);
    DPP_MIN_STAGE(v, 0x143);
    return (u32)__builtin_amdgcn_readlane((int)v, 63);
}

#define DPP_ADD_STAGE(v, ctrl)                                                  \
    v += __int_as_float(__builtin_amdgcn_update_dpp(                            \
        0, __float_as_int(v), (ctrl), 0xF, 0xF, false))

__device__ __forceinline__ float wave_sum_dpp(float v) {
    DPP_ADD_STAGE(v, 0x111);
    DPP_ADD_STAGE(v, 0x112);
    DPP_ADD_STAGE(v, 0x114);
    DPP_ADD_STAGE(v, 0x118);
    DPP_ADD_STAGE(v, 0x142);
    DPP_ADD_STAGE(v, 0x143);
    return __int_as_float(__builtin_amdgcn_readlane(__float_as_int(v), 63));
}

__device__ __forceinline__ u32 mbcnt64(u64 m) {
    return __builtin_amdgcn_mbcnt_hi((u32)(m >> 32),
                                     __builtin_amdgcn_mbcnt_lo((u32)m, 0));
}

__device__ __forceinline__ float np_quad(float x, float y, float z) {
#pragma clang fp contract(off)
    float q = (x * x + y * y) + z * z;
    return q;
}

// non-contractable add (pragma must open a compound statement)
__device__ __forceinline__ float np_add(float a, float b) {
#pragma clang fp contract(off)
    float r = a + b;
    return r;
}

// pass-1 key: s = -2*inner + quad_j  (bit-exact prefix of the full dist)
__device__ __forceinline__ float np_s(const float4& m2, const float4& p) {
#pragma clang fp contract(off)
    float t = (m2.x * p.x + m2.y * p.y) + m2.z * p.z;   // == -2*inner, bit-exact
    float s = t + p.w;
    return s;
}

// full dist: (s + quad_own), same association/bits as numpy
__device__ __forceinline__ float np_dist2(const float4& m2, const float4& p) {
#pragma clang fp contract(off)
    float dist = np_s(m2, p) + m2.w;
    return dist;
}

__device__ __forceinline__ float4 fold_m2(const float4& me) {
    return make_float4(-2.0f * me.x, -2.0f * me.y, -2.0f * me.z, me.w);
}

__device__ __forceinline__ u32 flip_bits(float dist) {
    u32 b = __float_as_uint(dist);
    return b ^ (0x80000000u | (u32)((int)b >> 31));
}

__device__ __forceinline__ u64 dist_key(float dist, int j) {
    return ((u64)flip_bits(dist) << 32) | (u32)j;
}

// rank-sort survivors in sl[0..cnt) (cnt<=124) and emit ranks 1..32
__device__ __forceinline__ void emit_rank(u64* sl, int cnt, int row, int lane,
                                          u16* __restrict__ edge_ws,
                                          float* __restrict__ dist_ws) {
    if (lane < 4) sl[cnt + lane] = ~0ull;   // pads for the unroll-4 overshoot
    u64 own1 = sl[lane];
    if (lane >= cnt) own1 = ~0ull;
    int r1 = 0;
    for (int i = 0; i < cnt; i += 4) {
        u64 s0 = sl[i], s1 = sl[i + 1], s2 = sl[i + 2], s3 = sl[i + 3];
        r1 += (s0 < own1) + (s1 < own1) + (s2 < own1) + (s3 < own1);
    }
    if (r1 >= 1 && r1 <= KNN) {
        u32 fk = (u32)(own1 >> 32);
        u32 bb = (fk & 0x80000000u) ? (fk ^ 0x80000000u) : ~fk;
        edge_ws[(size_t)row * KNN + r1 - 1] = (u16)(u32)own1;
        dist_ws[(size_t)row * KNN + r1 - 1] = __uint_as_float(bb);
    }
    if (cnt > 64) {   // uncommon (~1%), wave-uniform
        u64 own2 = (64 + lane < cnt) ? sl[64 + lane] : ~0ull;
        int r2 = 0;
        for (int i = 0; i < cnt; i += 4) {
            u64 s0 = sl[i], s1 = sl[i + 1], s2 = sl[i + 2], s3 = sl[i + 3];
            r2 += (s0 < own2) + (s1 < own2) + (s2 < own2) + (s3 < own2);
        }
        if (r2 >= 1 && r2 <= KNN) {
            u32 fk = (u32)(own2 >> 32);
            u32 bb = (fk & 0x80000000u) ? (fk ^ 0x80000000u) : ~fk;
            edge_ws[(size_t)row * KNN + r2 - 1] = (u16)(u32)own2;
            dist_ws[(size_t)row * KNN + r2 - 1] = __uint_as_float(bb);
        }
    }
}

// register-light exact fallback (cnt>124, ~never): 33 rescan-extract rounds
__device__ __attribute__((noinline)) void slow_row(const float4* sp, float4 m2,
                                                   int row, int lane,
                                                   u16* __restrict__ edge_ws,
                                                   float* __restrict__ dist_ws) {
    u64 thr = 0ull;   // all real keys are > 0 (flip==0 would require NaN dist)
    for (int s = 0; s <= KNN; ++s) {
        u64 best = ~0ull;
        for (int jj = 0; jj < 32; ++jj) {
            int j = jj * 64 + lane;
            u64 x = dist_key(np_dist2(m2, sp[j]), j);
            if (x > thr && x < best) best = x;
        }
        u32 bh = (u32)(best >> 32);
        u32 rh = wave_min_dpp(bh);
        u32 bl = (bh == rh) ? (u32)best : 0xFFFFFFFFu;
        u32 rl = wave_min_dpp(bl);
        thr = ((u64)rh << 32) | rl;
        if (s >= 1 && lane == s - 1) {
            u32 bb = (rh & 0x80000000u) ? (rh ^ 0x80000000u) : ~rh;
            edge_ws[(size_t)row * KNN + s - 1] = (u16)rl;
            dist_ws[(size_t)row * KNN + s - 1] = __uint_as_float(bb);
        }
    }
}

// one row's pass-2 from the register s-cache: d = sc[jj] + q (bit-identical),
// ballot-prefix compact of survivors into sl, emit. sp/m2 only for fallback.
__device__ __forceinline__ void compact_emit(const float4* sp, float4 m2,
                                             const float (&sc)[32], float pd,
                                             u64* sl, int row, int lane,
                                             u16* __restrict__ edge_ws,
                                             float* __restrict__ dist_ws) {
    u32 base = 0;
#pragma unroll
    for (int jj = 0; jj < 32; ++jj) {
        int j = jj * 64 + lane;
        float d = np_add(sc[jj], m2.w);
        bool s = d <= pd;
        u64 m = __ballot(s);
        u32 pos = base + mbcnt64(m);
        if (s && pos < 128) sl[pos] = ((u64)flip_bits(d) << 32) | (u32)j;
        base += (u32)__popcll(m);
    }
    if ((int)base <= 124) emit_rank(sl, (int)base, row, lane, edge_ws, dist_ws);
    else                  slow_row(sp, m2, row, lane, edge_ws, dist_ws);
}

__global__ __launch_bounds__(512, 4) void knn_kernel(const float* __restrict__ pos,
                                                     u16* __restrict__ edge_ws,
                                                     float* __restrict__ dist_ws,
                                                     const float* __restrict__ aw,
                                                     const float* __restrict__ sw,
                                                     float* __restrict__ aw4,
                                                     float* __restrict__ sw4) {
    __shared__ float4 sp[N];          // 32 KB
    __shared__ u64 slots[8][128];     // 8 KB (shared by a wave's two rows)
    const int tid  = threadIdx.x;
    const int lane = tid & 63;
    const int wave = tid >> 6;          // 0..7
    const int rb   = blockIdx.x * 16;   // 16 rows per block, same (b,c)
    const int bc   = rb >> 11;

    const float* posr = pos + (size_t)bc * (N * 3);
    for (int j = tid; j < N; j += 512) {
        float x = posr[3 * j], y = posr[3 * j + 1], z = posr[3 * j + 2];
        sp[j] = make_float4(x, y, z, np_quad(x, y, z));
    }

    // fused prep (block 0 only): repack weights into [f/4][m][f%4]
    if (blockIdx.x == 0) {
#pragma unroll
        for (int it = 0; it < 16; ++it) {
            int i = it * 512 + tid;           // i = f*64 + m
            int f = i >> 6, mm = i & 63;
            int idx = (f >> 2) * 256 + mm * 4 + (f & 3);
            aw4[idx] = aw[mm * 128 + f];
            sw4[idx] = sw[i];
        }
    }
    __syncthreads();

    const int rowA = rb + wave * 2, rowB = rowA + 1;
    const int nA = rowA & (N - 1), nB = nA + 1;
    const float4 m2A = fold_m2(sp[nA]);
    const float4 m2B = fold_m2(sp[nB]);

    // ---- pass 1: per-lane float min of s-keys, both rows; CACHE s in regs
    // (fully unrolled -> static indices -> registers, no scratch) ----
    float sA[32], sB[32];
    float mnA = __builtin_inff(), mnB = __builtin_inff();
#pragma unroll
    for (int jj = 0; jj < 32; ++jj) {
        int j = jj * 64 + lane;
        float4 p = sp[j];
        sA[jj] = np_s(m2A, p);
        sB[jj] = np_s(m2B, p);
        mnA = fminf(mnA, sA[jj]);
        mnB = fminf(mnB, sB[jj]);
    }

    // ---- pivots: 33rd-smallest lane min (interleaved float bitonic) ----
    float vA = mnA, vB = mnB;
#pragma unroll
    for (int k = 2; k <= 64; k <<= 1) {
#pragma unroll
        for (int j = k >> 1; j > 0; j >>= 1) {
            float oA = __int_as_float(__shfl_xor(__float_as_int(vA), j));
            float oB = __int_as_float(__shfl_xor(__float_as_int(vB), j));
            bool keepmin = (((lane & k) == 0) == ((lane & j) == 0));
            vA = ((oA < vA) == keepmin) ? oA : vA;
            vB = ((oB < vB) == keepmin) ? oB : vB;
        }
    }
    // pd = round(s_(33) + quad_own): bit-identical to the pivot on full dists
    // (order stats commute with the monotone map x -> round(x + c))
    float pdA = np_add(
        __int_as_float(__builtin_amdgcn_readlane(__float_as_int(vA), 32)), m2A.w);
    float pdB = np_add(
        __int_as_float(__builtin_amdgcn_readlane(__float_as_int(vB), 32)), m2B.w);

    // ---- pass 2: sequential per row from the register s-cache ----
    compact_emit(sp, m2A, sA, pdA, slots[wave], rowA, lane, edge_ws, dist_ws);
    compact_emit(sp, m2B, sB, pdB, slots[wave], rowB, lane, edge_ws, dist_ws);
}

// ---------------------------------------------------------------------------
// Kernel 2: angle features + gate + gated aggregation + two 128->64 matvecs.
// One wave per (b,n); 8 consecutive n (same b) per 512-thread block.
// All intermediates wave-private in LDS -> only ONE barrier (outv transpose).
// Phase C: float4 weights from global (VMEM pipe) x float4 theta/h broadcast
// from LDS; unroll 4 to bound in-flight float4 register pressure.
// ---------------------------------------------------------------------------
__global__ __launch_bounds__(512) void conv_kernel(
    const float* __restrict__ pos, const float* __restrict__ node_fea,
    const float* __restrict__ node_mask, const float* __restrict__ aw4,
    const float* __restrict__ sw4, const float* __restrict__ w1,
    const float* __restrict__ w2, const u16* __restrict__ edge_ws,
    const float* __restrict__ dist_ws, float* __restrict__ out) {
    __shared__ __align__(16) float theta_lds[8][128];  // [wave][f], f=kk*4+cc
    __shared__ float gate_lds[8][128];                 // [wave][cc*32+kk]
    __shared__ u16   edge_lds[8][128];                 // [wave][cc*32+kk]
    __shared__ __align__(16) float h_lds[8][128];      // [wave][f], f=cc*32+..
    __shared__ float gsum_lds[8][4];                   // [wave][cc]
    __shared__ float outv[8][65];                      // [n-offset][m], padded

    const int tid  = threadIdx.x;
    const int lane = tid & 63;
    const int wave = tid >> 6;             // 0..7

    const int row0 = blockIdx.x * 8;   // (b,n) row base, same b across block
    const int b    = row0 >> 11;
    const int n0   = row0 & (N - 1);
    const int row  = row0 + wave;
    const int n    = row & (N - 1);
    const float mval = node_mask[b * N + n];

    // gate scalar S = sum_m relu(w1[m]) * w2[m]
    float S = wave_sum_dpp(fmaxf(w1[lane], 0.f) * w2[lane]);

    // ---- Phase A: per (cc,kk) pair: direction, theta, gate (wave-private) ----
#pragma unroll
    for (int it = 0; it < 2; ++it) {
        int p  = it * 64 + lane;
        int cc = p >> 5, kk = p & 31;
        int rowc = (b * C + cc) * N + n;
        int e      = edge_ws[(size_t)rowc * KNN + kk];
        float dist = dist_ws[(size_t)rowc * KNN + kk];
        const float* pp = pos + (size_t)rowc * 3;
        const float* qp = pos + ((size_t)(b * C + cc) * N + e) * 3;
        float dx = qp[0] - pp[0], dy = qp[1] - pp[1], dz = qp[2] - pp[2];
        float nrm = fmaxf(sqrtf(dx * dx + dy * dy + dz * dz), 1e-12f);
        float inv = 1.0f / nrm;
        dx *= inv; dy *= inv; dz *= inv;
        int src = lane & 32;   // lane holding kk==0 for this cc-group
        float n0x = __shfl(dx, src), n0y = __shfl(dy, src), n0z = __shfl(dz, src);
        float cosv = (kk == 0) ? 1.f : (dx * n0x + dy * n0y + dz * n0z);
        theta_lds[wave][kk * 4 + cc] = cosv * mval;

        float g = fmaxf(dist * S, 0.f) * mval;
        float gate = 1.f / (1.f + expf(-g));
        gate_lds[wave][cc * 32 + kk] = gate;
        edge_lds[wave][cc * 32 + kk] = (u16)e;
        float gs = gate;
#pragma unroll
        for (int off = 1; off < 32; off <<= 1) gs += __shfl_xor(gs, off);
        if (kk == 0) gsum_lds[wave][cc] = gs;
    }

    // ---- Phase B: h[f] = sum_k gate * fea_cat (all 64 lanes gather) ----
    {
        int cc = lane >> 4, dd = lane & 15;
        const float* nf = node_fea + (size_t)(b * C + cc) * N * D;
        float own = nf[(size_t)n * D + dd];
        h_lds[wave][cc * 32 + dd] = own * mval * gsum_lds[wave][cc];
        float acc = 0.f;
#pragma unroll
        for (int k = 0; k < 32; ++k) {
            int e = edge_lds[wave][cc * 32 + k];
            acc += gate_lds[wave][cc * 32 + k] * nf[(size_t)e * D + dd];
        }
        h_lds[wave][cc * 32 + 16 + dd] = acc * mval;
    }

    // ---- Phase C: m = lane; two 128->64 matvecs (float4) + epilogue ----
    {
        const float4* wa4 = (const float4*)aw4;
        const float4* wv4 = (const float4*)sw4;
        const float4* th4 = (const float4*)(&theta_lds[wave][0]);
        const float4* hh4 = (const float4*)(&h_lds[wave][0]);
        float fs = 0.f, fe = 0.f;
#pragma unroll 4
        for (int f4 = 0; f4 < 32; ++f4) {
            float4 wa = wa4[f4 * 64 + lane];
            float4 wv = wv4[f4 * 64 + lane];
            float4 tv = th4[f4];
            float4 hv = hh4[f4];
            fs += wa.x * tv.x + wa.y * tv.y + wa.z * tv.z + wa.w * tv.w;
            fe += wv.x * hv.x + wv.y * hv.y + wv.z * hv.z + wv.w * hv.w;
        }
        float v = fs + fe;
        v = (v > 0.f) ? v : 0.01f * v;
        outv[wave][lane] = v * mval;
    }
    __syncthreads();   // the only cross-wave handoff (outv transpose)

    // store: thread t -> m = t>>3, n-offset j = t&7
    {
        int m = tid >> 3, j = tid & 7;
        out[((size_t)(b * 64 + m)) * N + n0 + j] = outv[j][m];
    }
}

// ---------------------------------------------------------------------------
extern "C" void kernel_launch(void* const* d_in, const int* in_sizes, int n_in,
                              void* d_out, int out_size, void* d_ws, size_t ws_size,
                              hipStream_t stream) {
    const float* pos       = (const float*)d_in[0];
    const float* node_fea  = (const float*)d_in[1];
    const float* node_mask = (const float*)d_in[2];
    const float* aw        = (const float*)d_in[3];
    const float* sw        = (const float*)d_in[4];
    const float* w1        = (const float*)d_in[5];
    const float* w2        = (const float*)d_in[6];
    float* out = (float*)d_out;

    // ws: dist f32 4 MB | edge u16 2 MB | aw4 32 KB | sw4 32 KB  (~6.1 MB)
    float* dist_ws = (float*)d_ws;
    u16*   edge_ws = (u16*)((char*)d_ws + 4u * 1024 * 1024);
    float* aw4     = (float*)((char*)d_ws + 6u * 1024 * 1024);
    float* sw4     = (float*)((char*)d_ws + 6u * 1024 * 1024 + 32u * 1024);

    knn_kernel<<<BS * C * N / 16, 512, 0, stream>>>(pos, edge_ws, dist_ws,
                                                    aw, sw, aw4, sw4);
    conv_kernel<<<BS * N / 8, 512, 0, stream>>>(pos, node_fea, node_mask, aw4, sw4,
                                                w1, w2, edge_ws, dist_ws, out);
}